// Round 12
// baseline (202.736 us; speedup 1.0000x reference)
//
#include <hip/hip_runtime.h>
#include <hip/hip_bf16.h>

// B=512, T=2048, S=16, H=128, A=4.  NTOK = 1,048,576 tokens.
// Transposed MFMA chain; tokens live in lanes; D layout == B layout (K16).
// Numerics: r11-verified base (absmax 0.125) with ONE change: z1-chain rcp
// replaced by bit-trick + 1 Newton (full-rate).  z2-chain keeps v_rcp.
// Ledger (measured):
//   r8/r11: 115.4/116.5us, VALU 69-70 + MFMA 33-34, 3 waves/SIMD, no spill
//   r11 diagnostic: half8+shufflevector plumbing OK (absmax exactly 0.125)
//     => r9 K32 fail was layout-semantic.  K32 RETIRED: MFMA-busy (1450
//     cyc/tile, 87 x ~16cyc K16) < VALU-busy (3070) and they co-issue, so
//     MFMA cuts don't move the wall.
//   Cycle model (r11 counters): wall 4390 cyc/tile; trans ~16 cyc issue
//     => 128 trans = 2050 cyc = 47% of wall.  THE target is trans.
// Round-18: z1 rcp -> Newton (sensitivity-split):
//   z2 (32 rcp): s2-err sensitivity K~3e4 (r5->r7 calibration) => Newton-2's
//     6e-6 rel would blow absmax past 1.  KEEP v_rcp.
//   z1 (32 rcp): feeds f16 + O(1)-sensitivity ua => bit-trick+1-Newton
//     (rel ~2.5e-3 -> u err ~1e-2, negligible).  34->24 cyc per sigmoid:
//     -320 cyc/tile = -7.3% wall.
// Kept: KC fold, R-form sech2, hp/ua via R-MFMAs, half8 LDS packing,
// sv prefetch, pkrtz split4, rcp-lam, NBLK=2048, biases in LDS, (256,4).
// Spill tripwire: WRITE >> 16384 KB.  absmax tripwire: > 0.35 => revert
// to v_rcp on z1 / add 2nd Newton.
#define HDIM 128
#define SDIM 16
#define ADIM 4
#define NTOK (512 * 2048)
#define NTILE (NTOK / 16)      // 65536 16-token tiles
#define NBLK 2048
#define WPB 4                  // waves per 256-thread block
#define TPW (NTILE / (NBLK * WPB))   // 8 tiles per wave

#define KC 2.88539008177792681f      // 2*log2(e)

typedef _Float16 half4 __attribute__((ext_vector_type(4)));
typedef _Float16 half8 __attribute__((ext_vector_type(8)));
typedef float f32x4 __attribute__((ext_vector_type(4)));

__device__ __forceinline__ f32x4 mm(half4 a, half4 b, f32x4 c) {
    return __builtin_amdgcn_mfma_f32_16x16x16f16(a, b, c, 0, 0, 0);
}
__device__ __forceinline__ half4 lo4(half8 v) {
    return __builtin_shufflevector(v, v, 0, 1, 2, 3);
}
__device__ __forceinline__ half4 hi4(half8 v) {
    return __builtin_shufflevector(v, v, 4, 5, 6, 7);
}
__device__ __forceinline__ half8 cat(half4 a, half4 b) {
    return __builtin_shufflevector(a, b, 0, 1, 2, 3, 4, 5, 6, 7);
}
// R = 1/(2^z + 1) — ACCURATE path (z2 chain): v_rcp (2^-22 rel).
__device__ __forceinline__ f32x4 sigR4(f32x4 z) {
    f32x4 r;
    r.x = __builtin_amdgcn_rcpf(__builtin_amdgcn_exp2f(z.x) + 1.0f);
    r.y = __builtin_amdgcn_rcpf(__builtin_amdgcn_exp2f(z.y) + 1.0f);
    r.z = __builtin_amdgcn_rcpf(__builtin_amdgcn_exp2f(z.z) + 1.0f);
    r.w = __builtin_amdgcn_rcpf(__builtin_amdgcn_exp2f(z.w) + 1.0f);
    return r;
}
// FAST path (z1 chain): bit-trick seed + 1 Newton (full-rate, ~2.5e-3 rel).
// d = 2^z + 1 in [1, ~1e12] — always normal, no edge cases.
__device__ __forceinline__ float nrcp1(float d) {
    float y = __uint_as_float(0x7EF311C3u - __float_as_uint(d));
    return y * __builtin_fmaf(-d, y, 2.0f);
}
__device__ __forceinline__ f32x4 sigR4f(f32x4 z) {
    f32x4 r;
    r.x = nrcp1(__builtin_amdgcn_exp2f(z.x) + 1.0f);
    r.y = nrcp1(__builtin_amdgcn_exp2f(z.y) + 1.0f);
    r.z = nrcp1(__builtin_amdgcn_exp2f(z.z) + 1.0f);
    r.w = nrcp1(__builtin_amdgcn_exp2f(z.w) + 1.0f);
    return r;
}
__device__ __forceinline__ half4 toh_rtz(f32x4 v) { // packed RTZ, 2 insts
    auto a = __builtin_amdgcn_cvt_pkrtz(v.x, v.y);  // __fp16 x2
    auto b = __builtin_amdgcn_cvt_pkrtz(v.z, v.w);
    half4 h;
    h.x = (_Float16)a.x; h.y = (_Float16)a.y;
    h.z = (_Float16)b.x; h.w = (_Float16)b.y;
    return h;
}
// split fp32 into f16 hi + lo (x ~= hi + lo).  RTZ on hi compensated by lo.
__device__ __forceinline__ void split4(f32x4 v, half4& hi, half4& lo) {
    hi = toh_rtz(v);
    f32x4 r;
    r.x = v.x - (float)hi.x; r.y = v.y - (float)hi.y;
    r.z = v.z - (float)hi.z; r.w = v.w - (float)hi.w;
    lo = toh_rtz(r);
}
__device__ __forceinline__ float dot4(f32x4 a, f32x4 b) {
    return a.x*b.x + a.y*b.y + a.z*b.z + a.w*b.w;
}
__device__ __forceinline__ float redq(float v) {   // sum over the 4 lane-quads
    v += __shfl_xor(v, 16, 64);
    v += __shfl_xor(v, 32, 64);
    return v;
}

__global__ __launch_bounds__(256, 4) void cbf_qp_kernel(
    const float* __restrict__ state,
    const float* __restrict__ Wc1, const float* __restrict__ bc1,
    const float* __restrict__ Wc2, const float* __restrict__ bc2,
    const float* __restrict__ Wh1, const float* __restrict__ bh1,
    const float* __restrict__ wh2, const float* __restrict__ bh2,
    const float* __restrict__ Wf,  const float* __restrict__ bf,
    const float* __restrict__ Wg,  const float* __restrict__ bg,
    float* __restrict__ out)
{
    // ---- LDS weight A-frags ----------------------------------------------
    __shared__ __align__(16) half4 az1_s[8 * 64];    // KC*Wc1^T
    __shared__ __align__(16) half4 aua_s[8 * 64];    // -4*Wc2^T (rows>=4 zero)
    __shared__ __align__(16) half4 ahp_s[8 * 64];    // 2*wh2 row 0, else 0
    __shared__ __align__(16) half8 az2_s[8 * 64];    // {KC*Wh1^T hi, lo}
    __shared__ __align__(16) half8 adh_s[8 * 64];    // {4(Wh1.*wh2) LO, HI}
    __shared__ __align__(16) half8 af_s[64];         // {Wf^T hi, lo}
    __shared__ __align__(16) half8 ag_s[4 * 64];     // {Wg^T perm hi, lo}
    __shared__ __align__(16) float bgt_s[64];        // bgt[a][s] = bg[s*4+a]
    __shared__ __align__(16) float bc1_s[HDIM];      // KC*bc1
    __shared__ __align__(16) float bh1_s[HDIM];      // KC*bh1
    __shared__ __align__(16) float ua0_s[4];         // 2*colsum(Wc2) + 2*bc2
    __shared__ float w2b_s;                          // sum(wh2) + bh2

    const int tid = threadIdx.x;

    // ---- per-block pack: raw global weights -> LDS frags ------------------
    // A-frag layout (K16): lane l holds A[m][k], m = l&15, k = (l>>4)*4 + e
    for (int idx = tid; idx < 8 * 64; idx += 256) {
        const int c = idx >> 6, lane = idx & 63;
        const int m = lane & 15, q = lane >> 4;
        half4 hz1, hua, hhp, h2h, h2l, hdh, hdl;
        #pragma unroll
        for (int e = 0; e < 4; ++e) {
            const int k = q * 4 + e;
            const int j = c * 16 + k;
            hz1[e] = (_Float16)(KC * Wc1[k * HDIM + c*16 + m]);
            hua[e] = (m < ADIM) ? (_Float16)(-4.0f * Wc2[j * ADIM + m])
                                : (_Float16)0.f;
            hhp[e] = (m == 0) ? (_Float16)(2.0f * wh2[j]) : (_Float16)0.f;
            float w2 = KC * Wh1[k * HDIM + c*16 + m];
            _Float16 hh = (_Float16)w2;
            h2h[e] = hh; h2l[e] = (_Float16)(w2 - (float)hh);
            float wd = 4.0f * Wh1[m * HDIM + j] * wh2[j];   // 4x: sech2=4*s2'
            _Float16 hd = (_Float16)wd;
            hdh[e] = hd; hdl[e] = (_Float16)(wd - (float)hd);
        }
        az1_s[idx] = hz1;  aua_s[idx] = hua;  ahp_s[idx] = hhp;
        az2_s[idx] = cat(h2h, h2l);    // {hi, lo}
        adh_s[idx] = cat(hdl, hdh);    // {lo, hi}
    }
    if (tid < 64) {                                  // Wf^T split
        const int m = tid & 15, q = tid >> 4;
        half4 fh, fl;
        #pragma unroll
        for (int e = 0; e < 4; ++e) {
            float w = Wf[(q*4+e) * SDIM + m];
            _Float16 h = (_Float16)w;
            fh[e] = h; fl[e] = (_Float16)(w - (float)h);
        }
        af_s[tid] = cat(fh, fl);
    }
    {                                                // Wg^T row-permuted split
        const int a = tid >> 6, lane = tid & 63;
        const int m = lane & 15, q = lane >> 4;      // m = s index
        half4 gh, gl;
        #pragma unroll
        for (int e = 0; e < 4; ++e) {
            float w = Wg[(q*4+e) * 64 + m*4 + a];
            _Float16 h = (_Float16)w;
            gh[e] = h; gl[e] = (_Float16)(w - (float)h);
        }
        ag_s[tid] = cat(gh, gl);
    }
    if (tid < 64)                                    // bgt[a][s] = bg[s*4+a]
        bgt_s[(tid >> 4) * 16 + (tid & 15)] = bg[(tid & 15) * 4 + (tid >> 4)];
    if (tid < HDIM) {
        bc1_s[tid] = KC * bc1[tid];
        bh1_s[tid] = KC * bh1[tid];
    }
    if (tid < 4) {                                   // ua const: 2*colsum+2*bc2
        float s = 2.0f * bc2[tid];
        for (int j = 0; j < HDIM; ++j) s += 2.0f * Wc2[j * ADIM + tid];
        ua0_s[tid] = s;
    }
    if (tid == 0) {                                  // W2B = sum(wh2)+bh2
        float s = bh2[0];
        for (int j = 0; j < HDIM; ++j) s += wh2[j];
        w2b_s = s;
    }
    __syncthreads();

    // ---- main: 8 contiguous 16-token tiles per wave -----------------------
    const int lane = tid & 63;
    const int q = lane >> 4, n = lane & 15;
    const int wid = blockIdx.x * WPB + (tid >> 6);

    f32x4 bfC = *(const f32x4*)(bf + q*4);
    f32x4 uaC;                                       // ua const in q0, else 0
    {
        f32x4 u0 = *(const f32x4*)(ua0_s);
        uaC.x = q == 0 ? u0.x : 0.f; uaC.y = q == 0 ? u0.y : 0.f;
        uaC.z = q == 0 ? u0.z : 0.f; uaC.w = q == 0 ? u0.w : 0.f;
    }
    const float w2b = w2b_s;

    // prime prefetch
    f32x4 sv = *(const f32x4*)(state + (size_t)(wid*TPW*16 + n) * SDIM + q*4);

    for (int it = 0; it < TPW; ++it) {
        const int tile = wid * TPW + it;
        const int nxt = (it + 1 < TPW) ? tile + 1 : tile;
        f32x4 svn = *(const f32x4*)(state + (size_t)(nxt*16 + n) * SDIM + q*4);

        half4 bsh, bsl;
        split4(sv, bsh, bsl);

        // Accumulators: ua, hp, dhA, dhBC.
        f32x4 uaA  = uaC;
        f32x4 hpA  = {0.f, 0.f, 0.f, 0.f};
        f32x4 dhA  = {0.f, 0.f, 0.f, 0.f};
        f32x4 dhBC = {0.f, 0.f, 0.f, 0.f};
        #pragma unroll 2
        for (int c = 0; c < 8; ++c) {
            // ---- low-precision chain: z1' -> R1 (fast Newton rcp) -> ua
            f32x4 b1 = *(const f32x4*)(&bc1_s[c*16 + q*4]);
            f32x4 z1 = mm(az1_s[c*64 + lane], bsh, b1);   // = 2log2e * z1
            f32x4 R1 = sigR4f(z1);
            uaA = mm(aua_s[c*64 + lane], toh_rtz(R1), uaA);

            // ---- high-precision chain: z2' (split x split, 3x K16)
            f32x4 b2v = *(const f32x4*)(&bh1_s[c*16 + q*4]);
            half8 a2 = az2_s[c*64 + lane];                // one b128 read
            half4 a2h = lo4(a2), a2l = hi4(a2);
            f32x4 z2 = mm(a2h, bsl, b2v);
            z2 = mm(a2l, bsh, z2);
            z2 = mm(a2h, bsh, z2);                        // = 2log2e * z2
            f32x4 R2 = sigR4(z2);                         // ACCURATE rcp
            // hp via MFMA: row0-only A, B = R2 f16 (D layout == B layout)
            hpA = mm(ahp_s[c*64 + lane], toh_rtz(R2), hpA);
            // s2' = R(1-R) = sech^2/4 (4 folded into adh)
            f32x4 s2;
            s2.x = __builtin_fmaf(-R2.x, R2.x, R2.x);
            s2.y = __builtin_fmaf(-R2.y, R2.y, R2.y);
            s2.z = __builtin_fmaf(-R2.z, R2.z, R2.z);
            s2.w = __builtin_fmaf(-R2.w, R2.w, R2.w);
            half4 s2h, s2l;
            split4(s2, s2h, s2l);
            half8 ad = adh_s[c*64 + lane];                // one b128 read
            half4 adl = lo4(ad), adhh = hi4(ad);
            dhA  = mm(adhh, s2h, dhA);
            dhBC = mm(adl,  s2h, dhBC);
            dhBC = mm(adhh, s2l, dhBC);
        }
        f32x4 ua = uaA;
        f32x4 dh = dhA + dhBC;
        const float hp = hpA.x;            // complete at q0 (rows 1-15 zero)

        // f^T (rows = s) — split path, 3x K16
        half8 af = af_s[lane];
        half4 fh = lo4(af), fl = hi4(af);
        f32x4 fD = mm(fh, bsl, bfC);
        fD = mm(fl, bsh, fD);
        fD = mm(fh, bsh, fD);

        // right = W2B - hp + redq(dh.f)
        float right = w2b - hp + redq(dot4(dh, fD));

        float l0, l1, l2, l3;
        {
            half8 ag = ag_s[0*64 + lane];
            half4 gh = lo4(ag), gl = hi4(ag);
            f32x4 bgC = *(const f32x4*)(&bgt_s[0*16 + q*4]);
            f32x4 G = mm(gh, bsl, bgC); G = mm(gl, bsh, G); G = mm(gh, bsh, G);
            l0 = -redq(dot4(dh, G));
        }
        {
            half8 ag = ag_s[1*64 + lane];
            half4 gh = lo4(ag), gl = hi4(ag);
            f32x4 bgC = *(const f32x4*)(&bgt_s[1*16 + q*4]);
            f32x4 G = mm(gh, bsl, bgC); G = mm(gl, bsh, G); G = mm(gh, bsh, G);
            l1 = -redq(dot4(dh, G));
        }
        {
            half8 ag = ag_s[2*64 + lane];
            half4 gh = lo4(ag), gl = hi4(ag);
            f32x4 bgC = *(const f32x4*)(&bgt_s[2*16 + q*4]);
            f32x4 G = mm(gh, bsl, bgC); G = mm(gl, bsh, G); G = mm(gh, bsh, G);
            l2 = -redq(dot4(dh, G));
        }
        {
            half8 ag = ag_s[3*64 + lane];
            half4 gh = lo4(ag), gl = hi4(ag);
            f32x4 bgC = *(const f32x4*)(&bgt_s[3*16 + q*4]);
            f32x4 G = mm(gh, bsl, bgC); G = mm(gl, bsh, G); G = mm(gh, bsh, G);
            l3 = -redq(dot4(dh, G));
        }

        // ua rows >= 4 zero, const folded: q0 lanes hold complete u_unc.
        float u0 = ua.x, u1 = ua.y, u2 = ua.z, u3 = ua.w;

        float viol = l0*u0 + l1*u1 + l2*u2 + l3*u3 - right;
        float lsq  = l0*l0 + l1*l1 + l2*l2 + l3*l3;
        float lam  = viol > 0.f
                   ? viol * __builtin_amdgcn_rcpf(lsq + 1e-8f) : 0.f;

        if (q == 0) {                      // lanes 0-15 store their token
            f32x4 uo;
            uo.x = u0 - lam*l0; uo.y = u1 - lam*l1;
            uo.z = u2 - lam*l2; uo.w = u3 - lam*l3;
            *(f32x4*)(out + (size_t)(tile*16 + n) * ADIM) = uo;
        }

        sv = svn;
    }
}

extern "C" void kernel_launch(void* const* d_in, const int* in_sizes, int n_in,
                              void* d_out, int out_size, void* d_ws, size_t ws_size,
                              hipStream_t stream) {
    (void)in_sizes; (void)n_in; (void)d_ws; (void)ws_size; (void)out_size;
    const float* state = (const float*)d_in[0];
    const float* Wc1   = (const float*)d_in[1];
    const float* bc1   = (const float*)d_in[2];
    const float* Wc2   = (const float*)d_in[3];
    const float* bc2   = (const float*)d_in[4];
    const float* Wh1   = (const float*)d_in[5];
    const float* bh1   = (const float*)d_in[6];
    const float* wh2   = (const float*)d_in[7];
    const float* bh2   = (const float*)d_in[8];
    const float* Wf    = (const float*)d_in[9];
    const float* bf    = (const float*)d_in[10];
    const float* Wg    = (const float*)d_in[11];
    const float* bg    = (const float*)d_in[12];
    float* out = (float*)d_out;

    hipLaunchKernelGGL(cbf_qp_kernel, dim3(NBLK), dim3(256), 0, stream,
                       state, Wc1, bc1, Wc2, bc2, Wh1, bh1, wh2, bh2,
                       Wf, bf, Wg, bg, out);
}

// Round 13
// 202.296 us; speedup vs baseline: 1.0022x; 1.0022x over previous
//
#include <hip/hip_runtime.h>
#include <hip/hip_bf16.h>

// B=512, T=2048, S=16, H=128, A=4.  NTOK = 1,048,576 tokens.
// Transposed MFMA chain; tokens live in lanes; D layout == B layout (K16).
// Numerics: r11-verified math (absmax 0.125).  r12's Newton rcp REVERTED
// (measured: +3% VALUBusy, +2% time — rcp issue ~= 3 full-rate ops).
// Ledger (measured):
//   r8/r11: 115.4/116.5us, VALU ~70 + MFMA ~34, 3 waves/SIMD, no spill
//   r12: Newton rcp on z1 -> REGRESSION (revert).  Issue-count surgery
//     exhausted; residual is 30% VALU-idle = latency stalls at 3 waves.
//   r4: (256,5) spilled with the OLD heavy body (22+ acc regs, cap 102).
//     Body now 16 acc regs -> retry the cap with margin.
// Round-19: occupancy 3->4/5 waves/SIMD.
//  (o) ahp_s MERGED into aua_s row 4 (ua output rows>=4 land in q>=1
//      lanes, never read): A rows 0-3 = -4Wc2^T, row 4 = 2wh2, 5-15 = 0.
//      R1-MFMA (ua) and R2-MFMA (hp) share the A-frag; hp is bitwise
//      identical, now in q1 lanes' .x -> one shfl_xor(16) in epilogue.
//      -4 KB LDS (35.3 -> ~31 KB => 5 blocks/CU fit), -8 LDS reads/tile.
//  (p) __launch_bounds__(256,5): cap ~102 regs -> 5 waves/SIMD target.
//      Live-set est 85-95.  SPILL TRIPWIRE: WRITE_SIZE >> 16384 KB =>
//      next round revert to (256,4) KEEPING the merge.
// Kept: KC fold, R-form sech2, v_rcp both chains, half8 LDS packing,
// sv prefetch, pkrtz split4, rcp-lam, NBLK=2048, biases in LDS.
#define HDIM 128
#define SDIM 16
#define ADIM 4
#define NTOK (512 * 2048)
#define NTILE (NTOK / 16)      // 65536 16-token tiles
#define NBLK 2048
#define WPB 4                  // waves per 256-thread block
#define TPW (NTILE / (NBLK * WPB))   // 8 tiles per wave

#define KC 2.88539008177792681f      // 2*log2(e)

typedef _Float16 half4 __attribute__((ext_vector_type(4)));
typedef _Float16 half8 __attribute__((ext_vector_type(8)));
typedef float f32x4 __attribute__((ext_vector_type(4)));

__device__ __forceinline__ f32x4 mm(half4 a, half4 b, f32x4 c) {
    return __builtin_amdgcn_mfma_f32_16x16x16f16(a, b, c, 0, 0, 0);
}
__device__ __forceinline__ half4 lo4(half8 v) {
    return __builtin_shufflevector(v, v, 0, 1, 2, 3);
}
__device__ __forceinline__ half4 hi4(half8 v) {
    return __builtin_shufflevector(v, v, 4, 5, 6, 7);
}
__device__ __forceinline__ half8 cat(half4 a, half4 b) {
    return __builtin_shufflevector(a, b, 0, 1, 2, 3, 4, 5, 6, 7);
}
// R = 1/(2^z + 1) (z PRE-SCALED by 2log2e via packed weights).
// tanh(x) = 1 - 2R;  sech^2(x) = 4R(1-R).
__device__ __forceinline__ f32x4 sigR4(f32x4 z) {
    f32x4 r;
    r.x = __builtin_amdgcn_rcpf(__builtin_amdgcn_exp2f(z.x) + 1.0f);
    r.y = __builtin_amdgcn_rcpf(__builtin_amdgcn_exp2f(z.y) + 1.0f);
    r.z = __builtin_amdgcn_rcpf(__builtin_amdgcn_exp2f(z.z) + 1.0f);
    r.w = __builtin_amdgcn_rcpf(__builtin_amdgcn_exp2f(z.w) + 1.0f);
    return r;
}
__device__ __forceinline__ half4 toh_rtz(f32x4 v) { // packed RTZ, 2 insts
    auto a = __builtin_amdgcn_cvt_pkrtz(v.x, v.y);  // __fp16 x2
    auto b = __builtin_amdgcn_cvt_pkrtz(v.z, v.w);
    half4 h;
    h.x = (_Float16)a.x; h.y = (_Float16)a.y;
    h.z = (_Float16)b.x; h.w = (_Float16)b.y;
    return h;
}
// split fp32 into f16 hi + lo (x ~= hi + lo).  RTZ on hi compensated by lo.
__device__ __forceinline__ void split4(f32x4 v, half4& hi, half4& lo) {
    hi = toh_rtz(v);
    f32x4 r;
    r.x = v.x - (float)hi.x; r.y = v.y - (float)hi.y;
    r.z = v.z - (float)hi.z; r.w = v.w - (float)hi.w;
    lo = toh_rtz(r);
}
__device__ __forceinline__ float dot4(f32x4 a, f32x4 b) {
    return a.x*b.x + a.y*b.y + a.z*b.z + a.w*b.w;
}
__device__ __forceinline__ float redq(float v) {   // sum over the 4 lane-quads
    v += __shfl_xor(v, 16, 64);
    v += __shfl_xor(v, 32, 64);
    return v;
}

__global__ __launch_bounds__(256, 5) void cbf_qp_kernel(
    const float* __restrict__ state,
    const float* __restrict__ Wc1, const float* __restrict__ bc1,
    const float* __restrict__ Wc2, const float* __restrict__ bc2,
    const float* __restrict__ Wh1, const float* __restrict__ bh1,
    const float* __restrict__ wh2, const float* __restrict__ bh2,
    const float* __restrict__ Wf,  const float* __restrict__ bf,
    const float* __restrict__ Wg,  const float* __restrict__ bg,
    float* __restrict__ out)
{
    // ---- LDS weight A-frags ----------------------------------------------
    __shared__ __align__(16) half4 az1_s[8 * 64];    // KC*Wc1^T
    __shared__ __align__(16) half4 aua_s[8 * 64];    // rows0-3:-4Wc2^T row4:2wh2
    __shared__ __align__(16) half8 az2_s[8 * 64];    // {KC*Wh1^T hi, lo}
    __shared__ __align__(16) half8 adh_s[8 * 64];    // {4(Wh1.*wh2) LO, HI}
    __shared__ __align__(16) half8 af_s[64];         // {Wf^T hi, lo}
    __shared__ __align__(16) half8 ag_s[4 * 64];     // {Wg^T perm hi, lo}
    __shared__ __align__(16) float bgt_s[64];        // bgt[a][s] = bg[s*4+a]
    __shared__ __align__(16) float bc1_s[HDIM];      // KC*bc1
    __shared__ __align__(16) float bh1_s[HDIM];      // KC*bh1
    __shared__ __align__(16) float ua0_s[4];         // 2*colsum(Wc2) + 2*bc2
    __shared__ float w2b_s;                          // sum(wh2) + bh2

    const int tid = threadIdx.x;

    // ---- per-block pack: raw global weights -> LDS frags ------------------
    // A-frag layout (K16): lane l holds A[m][k], m = l&15, k = (l>>4)*4 + e
    for (int idx = tid; idx < 8 * 64; idx += 256) {
        const int c = idx >> 6, lane = idx & 63;
        const int m = lane & 15, q = lane >> 4;
        half4 hz1, hua, h2h, h2l, hdh, hdl;
        #pragma unroll
        for (int e = 0; e < 4; ++e) {
            const int k = q * 4 + e;
            const int j = c * 16 + k;
            hz1[e] = (_Float16)(KC * Wc1[k * HDIM + c*16 + m]);
            // merged A: rows 0-3 ua weights, row 4 hp weights, 5-15 zero.
            // ua output rows>=4 / hp output rows!=4 are never read.
            hua[e] = (m < ADIM) ? (_Float16)(-4.0f * Wc2[j * ADIM + m])
                   : (m == 4)  ? (_Float16)(2.0f * wh2[j])
                               : (_Float16)0.f;
            float w2 = KC * Wh1[k * HDIM + c*16 + m];
            _Float16 hh = (_Float16)w2;
            h2h[e] = hh; h2l[e] = (_Float16)(w2 - (float)hh);
            float wd = 4.0f * Wh1[m * HDIM + j] * wh2[j];   // 4x: sech2=4*s2'
            _Float16 hd = (_Float16)wd;
            hdh[e] = hd; hdl[e] = (_Float16)(wd - (float)hd);
        }
        az1_s[idx] = hz1;  aua_s[idx] = hua;
        az2_s[idx] = cat(h2h, h2l);    // {hi, lo}
        adh_s[idx] = cat(hdl, hdh);    // {lo, hi}
    }
    if (tid < 64) {                                  // Wf^T split
        const int m = tid & 15, q = tid >> 4;
        half4 fh, fl;
        #pragma unroll
        for (int e = 0; e < 4; ++e) {
            float w = Wf[(q*4+e) * SDIM + m];
            _Float16 h = (_Float16)w;
            fh[e] = h; fl[e] = (_Float16)(w - (float)h);
        }
        af_s[tid] = cat(fh, fl);
    }
    {                                                // Wg^T row-permuted split
        const int a = tid >> 6, lane = tid & 63;
        const int m = lane & 15, q = lane >> 4;      // m = s index
        half4 gh, gl;
        #pragma unroll
        for (int e = 0; e < 4; ++e) {
            float w = Wg[(q*4+e) * 64 + m*4 + a];
            _Float16 h = (_Float16)w;
            gh[e] = h; gl[e] = (_Float16)(w - (float)h);
        }
        ag_s[tid] = cat(gh, gl);
    }
    if (tid < 64)                                    // bgt[a][s] = bg[s*4+a]
        bgt_s[(tid >> 4) * 16 + (tid & 15)] = bg[(tid & 15) * 4 + (tid >> 4)];
    if (tid < HDIM) {
        bc1_s[tid] = KC * bc1[tid];
        bh1_s[tid] = KC * bh1[tid];
    }
    if (tid < 4) {                                   // ua const: 2*colsum+2*bc2
        float s = 2.0f * bc2[tid];
        for (int j = 0; j < HDIM; ++j) s += 2.0f * Wc2[j * ADIM + tid];
        ua0_s[tid] = s;
    }
    if (tid == 0) {                                  // W2B = sum(wh2)+bh2
        float s = bh2[0];
        for (int j = 0; j < HDIM; ++j) s += wh2[j];
        w2b_s = s;
    }
    __syncthreads();

    // ---- main: 8 contiguous 16-token tiles per wave -----------------------
    const int lane = tid & 63;
    const int q = lane >> 4, n = lane & 15;
    const int wid = blockIdx.x * WPB + (tid >> 6);

    f32x4 bfC = *(const f32x4*)(bf + q*4);
    f32x4 uaC;                                       // ua const in q0, else 0
    {
        f32x4 u0 = *(const f32x4*)(ua0_s);
        uaC.x = q == 0 ? u0.x : 0.f; uaC.y = q == 0 ? u0.y : 0.f;
        uaC.z = q == 0 ? u0.z : 0.f; uaC.w = q == 0 ? u0.w : 0.f;
    }
    const float w2b = w2b_s;

    // prime prefetch
    f32x4 sv = *(const f32x4*)(state + (size_t)(wid*TPW*16 + n) * SDIM + q*4);

    for (int it = 0; it < TPW; ++it) {
        const int tile = wid * TPW + it;
        const int nxt = (it + 1 < TPW) ? tile + 1 : tile;
        f32x4 svn = *(const f32x4*)(state + (size_t)(nxt*16 + n) * SDIM + q*4);

        half4 bsh, bsl;
        split4(sv, bsh, bsl);

        // Accumulators: ua, hp, dhA, dhBC.
        f32x4 uaA  = uaC;
        f32x4 hpA  = {0.f, 0.f, 0.f, 0.f};
        f32x4 dhA  = {0.f, 0.f, 0.f, 0.f};
        f32x4 dhBC = {0.f, 0.f, 0.f, 0.f};
        #pragma unroll 2
        for (int c = 0; c < 8; ++c) {
            // ---- low-precision chain: z1' -> R1 -> ua
            f32x4 b1 = *(const f32x4*)(&bc1_s[c*16 + q*4]);
            f32x4 z1 = mm(az1_s[c*64 + lane], bsh, b1);   // = 2log2e * z1
            f32x4 R1 = sigR4(z1);
            half4 aua = aua_s[c*64 + lane];               // shared ua/hp A
            uaA = mm(aua, toh_rtz(R1), uaA);

            // ---- high-precision chain: z2' (split x split, 3x K16)
            f32x4 b2v = *(const f32x4*)(&bh1_s[c*16 + q*4]);
            half8 a2 = az2_s[c*64 + lane];                // one b128 read
            half4 a2h = lo4(a2), a2l = hi4(a2);
            f32x4 z2 = mm(a2h, bsl, b2v);
            z2 = mm(a2l, bsh, z2);
            z2 = mm(a2h, bsh, z2);                        // = 2log2e * z2
            f32x4 R2 = sigR4(z2);
            // hp via the SAME A (row 4 = 2wh2): hp lands in q1 lanes' .x
            hpA = mm(aua, toh_rtz(R2), hpA);
            // s2' = R(1-R) = sech^2/4 (4 folded into adh)
            f32x4 s2;
            s2.x = __builtin_fmaf(-R2.x, R2.x, R2.x);
            s2.y = __builtin_fmaf(-R2.y, R2.y, R2.y);
            s2.z = __builtin_fmaf(-R2.z, R2.z, R2.z);
            s2.w = __builtin_fmaf(-R2.w, R2.w, R2.w);
            half4 s2h, s2l;
            split4(s2, s2h, s2l);
            half8 ad = adh_s[c*64 + lane];                // one b128 read
            half4 adl = lo4(ad), adhh = hi4(ad);
            dhA  = mm(adhh, s2h, dhA);
            dhBC = mm(adl,  s2h, dhBC);
            dhBC = mm(adhh, s2l, dhBC);
        }
        f32x4 ua = uaA;
        f32x4 dh = dhA + dhBC;
        // hp = row 4 of the merged-A R2-MFMA = q1 lanes' reg .x; move to q0.
        const float hp = __shfl_xor(hpA.x, 16, 64);

        // f^T (rows = s) — split path, 3x K16
        half8 af = af_s[lane];
        half4 fh = lo4(af), fl = hi4(af);
        f32x4 fD = mm(fh, bsl, bfC);
        fD = mm(fl, bsh, fD);
        fD = mm(fh, bsh, fD);

        // right = W2B - hp + redq(dh.f)
        float right = w2b - hp + redq(dot4(dh, fD));

        float l0, l1, l2, l3;
        {
            half8 ag = ag_s[0*64 + lane];
            half4 gh = lo4(ag), gl = hi4(ag);
            f32x4 bgC = *(const f32x4*)(&bgt_s[0*16 + q*4]);
            f32x4 G = mm(gh, bsl, bgC); G = mm(gl, bsh, G); G = mm(gh, bsh, G);
            l0 = -redq(dot4(dh, G));
        }
        {
            half8 ag = ag_s[1*64 + lane];
            half4 gh = lo4(ag), gl = hi4(ag);
            f32x4 bgC = *(const f32x4*)(&bgt_s[1*16 + q*4]);
            f32x4 G = mm(gh, bsl, bgC); G = mm(gl, bsh, G); G = mm(gh, bsh, G);
            l1 = -redq(dot4(dh, G));
        }
        {
            half8 ag = ag_s[2*64 + lane];
            half4 gh = lo4(ag), gl = hi4(ag);
            f32x4 bgC = *(const f32x4*)(&bgt_s[2*16 + q*4]);
            f32x4 G = mm(gh, bsl, bgC); G = mm(gl, bsh, G); G = mm(gh, bsh, G);
            l2 = -redq(dot4(dh, G));
        }
        {
            half8 ag = ag_s[3*64 + lane];
            half4 gh = lo4(ag), gl = hi4(ag);
            f32x4 bgC = *(const f32x4*)(&bgt_s[3*16 + q*4]);
            f32x4 G = mm(gh, bsl, bgC); G = mm(gl, bsh, G); G = mm(gh, bsh, G);
            l3 = -redq(dot4(dh, G));
        }

        // ua rows >= 4 unread, const folded: q0 lanes hold complete u_unc.
        float u0 = ua.x, u1 = ua.y, u2 = ua.z, u3 = ua.w;

        float viol = l0*u0 + l1*u1 + l2*u2 + l3*u3 - right;
        float lsq  = l0*l0 + l1*l1 + l2*l2 + l3*l3;
        float lam  = viol > 0.f
                   ? viol * __builtin_amdgcn_rcpf(lsq + 1e-8f) : 0.f;

        if (q == 0) {                      // lanes 0-15 store their token
            f32x4 uo;
            uo.x = u0 - lam*l0; uo.y = u1 - lam*l1;
            uo.z = u2 - lam*l2; uo.w = u3 - lam*l3;
            *(f32x4*)(out + (size_t)(tile*16 + n) * ADIM) = uo;
        }

        sv = svn;
    }
}

extern "C" void kernel_launch(void* const* d_in, const int* in_sizes, int n_in,
                              void* d_out, int out_size, void* d_ws, size_t ws_size,
                              hipStream_t stream) {
    (void)in_sizes; (void)n_in; (void)d_ws; (void)ws_size; (void)out_size;
    const float* state = (const float*)d_in[0];
    const float* Wc1   = (const float*)d_in[1];
    const float* bc1   = (const float*)d_in[2];
    const float* Wc2   = (const float*)d_in[3];
    const float* bc2   = (const float*)d_in[4];
    const float* Wh1   = (const float*)d_in[5];
    const float* bh1   = (const float*)d_in[6];
    const float* wh2   = (const float*)d_in[7];
    const float* bh2   = (const float*)d_in[8];
    const float* Wf    = (const float*)d_in[9];
    const float* bf    = (const float*)d_in[10];
    const float* Wg    = (const float*)d_in[11];
    const float* bg    = (const float*)d_in[12];
    float* out = (float*)d_out;

    hipLaunchKernelGGL(cbf_qp_kernel, dim3(NBLK), dim3(256), 0, stream,
                       state, Wc1, bc1, Wc2, bc2, Wh1, bh1, wh2, bh2,
                       Wf, bf, Wg, bg, out);
}

// Round 14
// 199.549 us; speedup vs baseline: 1.0160x; 1.0138x over previous
//
#include <hip/hip_runtime.h>
#include <hip/hip_bf16.h>

// B=512, T=2048, S=16, H=128, A=4.  NTOK = 1,048,576 tokens.
// Transposed MFMA chain; tokens live in lanes; D layout == B layout (K16).
// Numerics: r11-verified math (absmax 0.125) + r13-verified aua/ahp merge.
// Ledger (measured):
//   r8:  115.4us  (256,4) no spill, VALU 70 / MFMA 34 / Occ 37.5
//   r11: 116.5us  + half8 LDS packing + sv prefetch (neutral), absmax 0.125
//   r12: Newton rcp -> REGRESSION (rcp issue ~= 3 full-rate ops). Reverted.
//   r13: (256,5) + merge -> spill (WRITE 24MB), Occ only 43.5, 118.2us.
//     OCCUPANCY LEVER RETIRED: true live-set ~150-160 regs (unified file);
//     caps below it spill; spill always costs more than the extra waves
//     buy (r1/r4/r13 all confirm).  Merge itself verified bitwise (0.125).
// Round-20: consolidation — (256,4) no-spill point + keep the merge:
//  (o) aua_s rows 0-3 = -4Wc2^T, row 4 = 2wh2 (hp), rows 5-15 = 0.
//      R1-MFMA (ua) and R2-MFMA (hp) share the A-frag; hp lands in q1
//      lanes' .x -> one shfl_xor(16).  -4 KB LDS, -8 LDS reads/tile.
// Kept: KC fold, R-form sech2, v_rcp both chains, half8 LDS packing,
// sv prefetch, pkrtz split4, rcp-lam, NBLK=2048, biases in LDS.
// Spill tripwire: WRITE_SIZE >> 16384 KB (expect exactly 16384).
#define HDIM 128
#define SDIM 16
#define ADIM 4
#define NTOK (512 * 2048)
#define NTILE (NTOK / 16)      // 65536 16-token tiles
#define NBLK 2048
#define WPB 4                  // waves per 256-thread block
#define TPW (NTILE / (NBLK * WPB))   // 8 tiles per wave

#define KC 2.88539008177792681f      // 2*log2(e)

typedef _Float16 half4 __attribute__((ext_vector_type(4)));
typedef _Float16 half8 __attribute__((ext_vector_type(8)));
typedef float f32x4 __attribute__((ext_vector_type(4)));

__device__ __forceinline__ f32x4 mm(half4 a, half4 b, f32x4 c) {
    return __builtin_amdgcn_mfma_f32_16x16x16f16(a, b, c, 0, 0, 0);
}
__device__ __forceinline__ half4 lo4(half8 v) {
    return __builtin_shufflevector(v, v, 0, 1, 2, 3);
}
__device__ __forceinline__ half4 hi4(half8 v) {
    return __builtin_shufflevector(v, v, 4, 5, 6, 7);
}
__device__ __forceinline__ half8 cat(half4 a, half4 b) {
    return __builtin_shufflevector(a, b, 0, 1, 2, 3, 4, 5, 6, 7);
}
// R = 1/(2^z + 1) (z PRE-SCALED by 2log2e via packed weights).
// tanh(x) = 1 - 2R;  sech^2(x) = 4R(1-R).
__device__ __forceinline__ f32x4 sigR4(f32x4 z) {
    f32x4 r;
    r.x = __builtin_amdgcn_rcpf(__builtin_amdgcn_exp2f(z.x) + 1.0f);
    r.y = __builtin_amdgcn_rcpf(__builtin_amdgcn_exp2f(z.y) + 1.0f);
    r.z = __builtin_amdgcn_rcpf(__builtin_amdgcn_exp2f(z.z) + 1.0f);
    r.w = __builtin_amdgcn_rcpf(__builtin_amdgcn_exp2f(z.w) + 1.0f);
    return r;
}
__device__ __forceinline__ half4 toh_rtz(f32x4 v) { // packed RTZ, 2 insts
    auto a = __builtin_amdgcn_cvt_pkrtz(v.x, v.y);  // __fp16 x2
    auto b = __builtin_amdgcn_cvt_pkrtz(v.z, v.w);
    half4 h;
    h.x = (_Float16)a.x; h.y = (_Float16)a.y;
    h.z = (_Float16)b.x; h.w = (_Float16)b.y;
    return h;
}
// split fp32 into f16 hi + lo (x ~= hi + lo).  RTZ on hi compensated by lo.
__device__ __forceinline__ void split4(f32x4 v, half4& hi, half4& lo) {
    hi = toh_rtz(v);
    f32x4 r;
    r.x = v.x - (float)hi.x; r.y = v.y - (float)hi.y;
    r.z = v.z - (float)hi.z; r.w = v.w - (float)hi.w;
    lo = toh_rtz(r);
}
__device__ __forceinline__ float dot4(f32x4 a, f32x4 b) {
    return a.x*b.x + a.y*b.y + a.z*b.z + a.w*b.w;
}
__device__ __forceinline__ float redq(float v) {   // sum over the 4 lane-quads
    v += __shfl_xor(v, 16, 64);
    v += __shfl_xor(v, 32, 64);
    return v;
}

__global__ __launch_bounds__(256, 4) void cbf_qp_kernel(
    const float* __restrict__ state,
    const float* __restrict__ Wc1, const float* __restrict__ bc1,
    const float* __restrict__ Wc2, const float* __restrict__ bc2,
    const float* __restrict__ Wh1, const float* __restrict__ bh1,
    const float* __restrict__ wh2, const float* __restrict__ bh2,
    const float* __restrict__ Wf,  const float* __restrict__ bf,
    const float* __restrict__ Wg,  const float* __restrict__ bg,
    float* __restrict__ out)
{
    // ---- LDS weight A-frags ----------------------------------------------
    __shared__ __align__(16) half4 az1_s[8 * 64];    // KC*Wc1^T
    __shared__ __align__(16) half4 aua_s[8 * 64];    // rows0-3:-4Wc2^T row4:2wh2
    __shared__ __align__(16) half8 az2_s[8 * 64];    // {KC*Wh1^T hi, lo}
    __shared__ __align__(16) half8 adh_s[8 * 64];    // {4(Wh1.*wh2) LO, HI}
    __shared__ __align__(16) half8 af_s[64];         // {Wf^T hi, lo}
    __shared__ __align__(16) half8 ag_s[4 * 64];     // {Wg^T perm hi, lo}
    __shared__ __align__(16) float bgt_s[64];        // bgt[a][s] = bg[s*4+a]
    __shared__ __align__(16) float bc1_s[HDIM];      // KC*bc1
    __shared__ __align__(16) float bh1_s[HDIM];      // KC*bh1
    __shared__ __align__(16) float ua0_s[4];         // 2*colsum(Wc2) + 2*bc2
    __shared__ float w2b_s;                          // sum(wh2) + bh2

    const int tid = threadIdx.x;

    // ---- per-block pack: raw global weights -> LDS frags ------------------
    // A-frag layout (K16): lane l holds A[m][k], m = l&15, k = (l>>4)*4 + e
    for (int idx = tid; idx < 8 * 64; idx += 256) {
        const int c = idx >> 6, lane = idx & 63;
        const int m = lane & 15, q = lane >> 4;
        half4 hz1, hua, h2h, h2l, hdh, hdl;
        #pragma unroll
        for (int e = 0; e < 4; ++e) {
            const int k = q * 4 + e;
            const int j = c * 16 + k;
            hz1[e] = (_Float16)(KC * Wc1[k * HDIM + c*16 + m]);
            // merged A: rows 0-3 ua weights, row 4 hp weights, 5-15 zero.
            hua[e] = (m < ADIM) ? (_Float16)(-4.0f * Wc2[j * ADIM + m])
                   : (m == 4)  ? (_Float16)(2.0f * wh2[j])
                               : (_Float16)0.f;
            float w2 = KC * Wh1[k * HDIM + c*16 + m];
            _Float16 hh = (_Float16)w2;
            h2h[e] = hh; h2l[e] = (_Float16)(w2 - (float)hh);
            float wd = 4.0f * Wh1[m * HDIM + j] * wh2[j];   // 4x: sech2=4*s2'
            _Float16 hd = (_Float16)wd;
            hdh[e] = hd; hdl[e] = (_Float16)(wd - (float)hd);
        }
        az1_s[idx] = hz1;  aua_s[idx] = hua;
        az2_s[idx] = cat(h2h, h2l);    // {hi, lo}
        adh_s[idx] = cat(hdl, hdh);    // {lo, hi}
    }
    if (tid < 64) {                                  // Wf^T split
        const int m = tid & 15, q = tid >> 4;
        half4 fh, fl;
        #pragma unroll
        for (int e = 0; e < 4; ++e) {
            float w = Wf[(q*4+e) * SDIM + m];
            _Float16 h = (_Float16)w;
            fh[e] = h; fl[e] = (_Float16)(w - (float)h);
        }
        af_s[tid] = cat(fh, fl);
    }
    {                                                // Wg^T row-permuted split
        const int a = tid >> 6, lane = tid & 63;
        const int m = lane & 15, q = lane >> 4;      // m = s index
        half4 gh, gl;
        #pragma unroll
        for (int e = 0; e < 4; ++e) {
            float w = Wg[(q*4+e) * 64 + m*4 + a];
            _Float16 h = (_Float16)w;
            gh[e] = h; gl[e] = (_Float16)(w - (float)h);
        }
        ag_s[tid] = cat(gh, gl);
    }
    if (tid < 64)                                    // bgt[a][s] = bg[s*4+a]
        bgt_s[(tid >> 4) * 16 + (tid & 15)] = bg[(tid & 15) * 4 + (tid >> 4)];
    if (tid < HDIM) {
        bc1_s[tid] = KC * bc1[tid];
        bh1_s[tid] = KC * bh1[tid];
    }
    if (tid < 4) {                                   // ua const: 2*colsum+2*bc2
        float s = 2.0f * bc2[tid];
        for (int j = 0; j < HDIM; ++j) s += 2.0f * Wc2[j * ADIM + tid];
        ua0_s[tid] = s;
    }
    if (tid == 0) {                                  // W2B = sum(wh2)+bh2
        float s = bh2[0];
        for (int j = 0; j < HDIM; ++j) s += wh2[j];
        w2b_s = s;
    }
    __syncthreads();

    // ---- main: 8 contiguous 16-token tiles per wave -----------------------
    const int lane = tid & 63;
    const int q = lane >> 4, n = lane & 15;
    const int wid = blockIdx.x * WPB + (tid >> 6);

    f32x4 bfC = *(const f32x4*)(bf + q*4);
    f32x4 uaC;                                       // ua const in q0, else 0
    {
        f32x4 u0 = *(const f32x4*)(ua0_s);
        uaC.x = q == 0 ? u0.x : 0.f; uaC.y = q == 0 ? u0.y : 0.f;
        uaC.z = q == 0 ? u0.z : 0.f; uaC.w = q == 0 ? u0.w : 0.f;
    }
    const float w2b = w2b_s;

    // prime prefetch
    f32x4 sv = *(const f32x4*)(state + (size_t)(wid*TPW*16 + n) * SDIM + q*4);

    for (int it = 0; it < TPW; ++it) {
        const int tile = wid * TPW + it;
        const int nxt = (it + 1 < TPW) ? tile + 1 : tile;
        f32x4 svn = *(const f32x4*)(state + (size_t)(nxt*16 + n) * SDIM + q*4);

        half4 bsh, bsl;
        split4(sv, bsh, bsl);

        // Accumulators: ua, hp, dhA, dhBC.
        f32x4 uaA  = uaC;
        f32x4 hpA  = {0.f, 0.f, 0.f, 0.f};
        f32x4 dhA  = {0.f, 0.f, 0.f, 0.f};
        f32x4 dhBC = {0.f, 0.f, 0.f, 0.f};
        #pragma unroll 2
        for (int c = 0; c < 8; ++c) {
            // ---- low-precision chain: z1' -> R1 -> ua
            f32x4 b1 = *(const f32x4*)(&bc1_s[c*16 + q*4]);
            f32x4 z1 = mm(az1_s[c*64 + lane], bsh, b1);   // = 2log2e * z1
            f32x4 R1 = sigR4(z1);
            half4 aua = aua_s[c*64 + lane];               // shared ua/hp A
            uaA = mm(aua, toh_rtz(R1), uaA);

            // ---- high-precision chain: z2' (split x split, 3x K16)
            f32x4 b2v = *(const f32x4*)(&bh1_s[c*16 + q*4]);
            half8 a2 = az2_s[c*64 + lane];                // one b128 read
            half4 a2h = lo4(a2), a2l = hi4(a2);
            f32x4 z2 = mm(a2h, bsl, b2v);
            z2 = mm(a2l, bsh, z2);
            z2 = mm(a2h, bsh, z2);                        // = 2log2e * z2
            f32x4 R2 = sigR4(z2);
            // hp via the SAME A (row 4 = 2wh2): hp lands in q1 lanes' .x
            hpA = mm(aua, toh_rtz(R2), hpA);
            // s2' = R(1-R) = sech^2/4 (4 folded into adh)
            f32x4 s2;
            s2.x = __builtin_fmaf(-R2.x, R2.x, R2.x);
            s2.y = __builtin_fmaf(-R2.y, R2.y, R2.y);
            s2.z = __builtin_fmaf(-R2.z, R2.z, R2.z);
            s2.w = __builtin_fmaf(-R2.w, R2.w, R2.w);
            half4 s2h, s2l;
            split4(s2, s2h, s2l);
            half8 ad = adh_s[c*64 + lane];                // one b128 read
            half4 adl = lo4(ad), adhh = hi4(ad);
            dhA  = mm(adhh, s2h, dhA);
            dhBC = mm(adl,  s2h, dhBC);
            dhBC = mm(adhh, s2l, dhBC);
        }
        f32x4 ua = uaA;
        f32x4 dh = dhA + dhBC;
        // hp = row 4 of the merged-A R2-MFMA = q1 lanes' reg .x; move to q0.
        const float hp = __shfl_xor(hpA.x, 16, 64);

        // f^T (rows = s) — split path, 3x K16
        half8 af = af_s[lane];
        half4 fh = lo4(af), fl = hi4(af);
        f32x4 fD = mm(fh, bsl, bfC);
        fD = mm(fl, bsh, fD);
        fD = mm(fh, bsh, fD);

        // right = W2B - hp + redq(dh.f)
        float right = w2b - hp + redq(dot4(dh, fD));

        float l0, l1, l2, l3;
        {
            half8 ag = ag_s[0*64 + lane];
            half4 gh = lo4(ag), gl = hi4(ag);
            f32x4 bgC = *(const f32x4*)(&bgt_s[0*16 + q*4]);
            f32x4 G = mm(gh, bsl, bgC); G = mm(gl, bsh, G); G = mm(gh, bsh, G);
            l0 = -redq(dot4(dh, G));
        }
        {
            half8 ag = ag_s[1*64 + lane];
            half4 gh = lo4(ag), gl = hi4(ag);
            f32x4 bgC = *(const f32x4*)(&bgt_s[1*16 + q*4]);
            f32x4 G = mm(gh, bsl, bgC); G = mm(gl, bsh, G); G = mm(gh, bsh, G);
            l1 = -redq(dot4(dh, G));
        }
        {
            half8 ag = ag_s[2*64 + lane];
            half4 gh = lo4(ag), gl = hi4(ag);
            f32x4 bgC = *(const f32x4*)(&bgt_s[2*16 + q*4]);
            f32x4 G = mm(gh, bsl, bgC); G = mm(gl, bsh, G); G = mm(gh, bsh, G);
            l2 = -redq(dot4(dh, G));
        }
        {
            half8 ag = ag_s[3*64 + lane];
            half4 gh = lo4(ag), gl = hi4(ag);
            f32x4 bgC = *(const f32x4*)(&bgt_s[3*16 + q*4]);
            f32x4 G = mm(gh, bsl, bgC); G = mm(gl, bsh, G); G = mm(gh, bsh, G);
            l3 = -redq(dot4(dh, G));
        }

        // ua rows >= 4 unread, const folded: q0 lanes hold complete u_unc.
        float u0 = ua.x, u1 = ua.y, u2 = ua.z, u3 = ua.w;

        float viol = l0*u0 + l1*u1 + l2*u2 + l3*u3 - right;
        float lsq  = l0*l0 + l1*l1 + l2*l2 + l3*l3;
        float lam  = viol > 0.f
                   ? viol * __builtin_amdgcn_rcpf(lsq + 1e-8f) : 0.f;

        if (q == 0) {                      // lanes 0-15 store their token
            f32x4 uo;
            uo.x = u0 - lam*l0; uo.y = u1 - lam*l1;
            uo.z = u2 - lam*l2; uo.w = u3 - lam*l3;
            *(f32x4*)(out + (size_t)(tile*16 + n) * ADIM) = uo;
        }

        sv = svn;
    }
}

extern "C" void kernel_launch(void* const* d_in, const int* in_sizes, int n_in,
                              void* d_out, int out_size, void* d_ws, size_t ws_size,
                              hipStream_t stream) {
    (void)in_sizes; (void)n_in; (void)d_ws; (void)ws_size; (void)out_size;
    const float* state = (const float*)d_in[0];
    const float* Wc1   = (const float*)d_in[1];
    const float* bc1   = (const float*)d_in[2];
    const float* Wc2   = (const float*)d_in[3];
    const float* bc2   = (const float*)d_in[4];
    const float* Wh1   = (const float*)d_in[5];
    const float* bh1   = (const float*)d_in[6];
    const float* wh2   = (const float*)d_in[7];
    const float* bh2   = (const float*)d_in[8];
    const float* Wf    = (const float*)d_in[9];
    const float* bf    = (const float*)d_in[10];
    const float* Wg    = (const float*)d_in[11];
    const float* bg    = (const float*)d_in[12];
    float* out = (float*)d_out;

    hipLaunchKernelGGL(cbf_qp_kernel, dim3(NBLK), dim3(256), 0, stream,
                       state, Wc1, bc1, Wc2, bc2, Wh1, bh1, wh2, bh2,
                       Wf, bf, Wg, bg, out);
}